// Round 18
// baseline (53.181 us; speedup 1.0000x reference)
//
#include <hip/hip_runtime.h>

#define DPROJ 1024

typedef short  bf16x8 __attribute__((ext_vector_type(8)));
typedef float  f32x4  __attribute__((ext_vector_type(4)));

__device__ __forceinline__ unsigned short f2bf(float f) {
  unsigned u = __builtin_bit_cast(unsigned, f);
  u += 0x7FFFu + ((u >> 16) & 1u);          // round-to-nearest-even
  return (unsigned short)(u >> 16);
}

__device__ __forceinline__ bf16x8 pack8(float4 lo, float4 hi) {
  bf16x8 r;
  r[0] = (short)f2bf(lo.x); r[1] = (short)f2bf(lo.y);
  r[2] = (short)f2bf(lo.z); r[3] = (short)f2bf(lo.w);
  r[4] = (short)f2bf(hi.x); r[5] = (short)f2bf(hi.y);
  r[6] = (short)f2bf(hi.z); r[7] = (short)f2bf(hi.w);
  return r;
}

__device__ __forceinline__ int bucket_of(int v) {
  return (v >= 200000) ? 3 : (v >= 40000) ? 2 : (v >= 20000) ? 1 : 0;
}

// ---------------------------------------------------------------------------
// Kernel 1 (PREP): all 680 blocks convert a proj slice fp32->bf16; the first
// nb blocks ALSO scatter their 256 tokens: each block ib computes its own
// per-bucket exclusive prefix by re-reading inp[0, ib*256) with ballot
// counting (redundant but tiny: sum = ~2 MB across all blocks) -> NO
// inter-block communication, no atomics, fully deterministic, stable
// (token-ascending lists). Block nb-1 publishes bucket totals.
// pb elem offsets: p0 @0, p1 @1048576, p2 @1310720, p3 @1376256 (2.72 MB).
// Entry packs (in-bucket row << 14) | token_id  (n = 16384 = 2^14).
// ---------------------------------------------------------------------------
__global__ __launch_bounds__(256) void prep(
    const float* __restrict__ p0, const float* __restrict__ p1,
    const float* __restrict__ p2, const float* __restrict__ p3,
    unsigned short* __restrict__ pb,
    const int* __restrict__ inp, int n, int nb,
    unsigned* __restrict__ lists, int* __restrict__ counts) {
  const int tid  = threadIdx.x;
  const int lane = tid & 63, w = tid >> 6;

  // ---- convert slice (all blocks)
  size_t base = ((size_t)blockIdx.x * 256 + tid) * 8;
  if (base < 1392640u) {
    const float* src;
    if      (base < 1048576u) src = p0 + base;
    else if (base < 1310720u) src = p1 + (base - 1048576u);
    else if (base < 1376256u) src = p2 + (base - 1310720u);
    else                      src = p3 + (base - 1376256u);
    float4 lo = reinterpret_cast<const float4*>(src)[0];
    float4 hi = reinterpret_cast<const float4*>(src)[1];
    *reinterpret_cast<bf16x8*>(pb + base) = pack8(lo, hi);
  }
  if (blockIdx.x >= (unsigned)nb) return;
  const int ib = blockIdx.x;

  // ---- per-bucket exclusive prefix over tokens [0, ib*256)
  int pre[4] = {0, 0, 0, 0};                // accumulated in lane 0 per wave
  for (int chunk = 0; chunk < ib; ++chunk) {
    int t = chunk * 256 + tid;
    int v = (t < n) ? inp[t] : -1;
    int b = (v < 0) ? -1 : bucket_of(v);
#pragma unroll
    for (int i = 0; i < 4; ++i) {
      unsigned long long m = __ballot(b == i);
      if (lane == 0) pre[i] += __popcll(m);
    }
  }

  // ---- own 256 tokens: counts + in-wave rank
  int t = ib * 256 + tid;
  int v = (t < n) ? inp[t] : -1;
  int b = (v < 0) ? -1 : bucket_of(v);
  int myrank = 0, own[4];
#pragma unroll
  for (int i = 0; i < 4; ++i) {
    unsigned long long m = __ballot(b == i);
    own[i] = __popcll(m);
    if (b == i) myrank = __popcll(m & ((1ull << lane) - 1ull));
  }

  __shared__ int s_pre[4][4];               // [wave][bucket]
  __shared__ int s_own[4][4];
  if (lane == 0) {
#pragma unroll
    for (int i = 0; i < 4; ++i) { s_pre[w][i] = pre[i]; s_own[w][i] = own[i]; }
  }
  __syncthreads();

  if (b >= 0) {
    int lo = (b == 3) ? 200000 : (b == 2) ? 40000 : (b == 1) ? 20000 : 0;
    int prefix = 0;
#pragma unroll
    for (int ww = 0; ww < 4; ++ww) prefix += s_pre[ww][b];
    for (int ww = 0; ww < w; ++ww) prefix += s_own[ww][b];
    lists[(size_t)b * n + prefix + myrank] = ((unsigned)(v - lo) << 14) | (unsigned)t;
  }

  if (ib == nb - 1 && tid < 4) {            // publish bucket totals
    int tot = 0;
#pragma unroll
    for (int ww = 0; ww < 4; ++ww) tot += s_pre[ww][tid] + s_own[ww][tid];
    counts[tid] = tot;
  }
}

// ---------------------------------------------------------------------------
// Heavy path: full-K (CHB chunks), prefetch distance 2 (two static register
// sets, fully unrolled). A gathered fp32 (converted in staging); B direct
// bf16 from L2-resident pb. LDS XOR swizzle byte ^= (row&7)<<4 (G4).
// [r16 verified, 35.5 us config]
// ---------------------------------------------------------------------------
template <int D, int CHB>
__device__ __forceinline__ void gemm_heavy(const float* __restrict__ emb,
                                           const unsigned short* __restrict__ pbD,
                                           const unsigned* __restrict__ list,
                                           int cnt, int r0, int c0,
                                           float* __restrict__ out, char* smem) {
  const int tid  = threadIdx.x;
  const int lane = tid & 63;
  const int w    = tid >> 6;
  const int wr   = w >> 1, wc = w & 1;     // 2x2 wave grid: 32 rows x 64 cols
  const int lr   = lane & 15, t16 = lane >> 4;

  char* Ab = smem;                          // A: 64 rows x 128 B  =  8 KB
  char* Bb = smem + 8192;                   // B: 128 cols x 128 B = 16 KB
  unsigned* toks = (unsigned*)(smem + 24576);

  if (tid < 64) {
    int p = r0 + tid;
    toks[tid] = (p < cnt) ? list[p] : 0u;   // pads -> row 0 (stores suppressed)
  }
  __syncthreads();

  int rowA[2], kkA[2], colB[4], kkB[4];
#pragma unroll
  for (int i = 0; i < 2; ++i) {
    int g = tid + i * 256;
    rowA[i] = g >> 3; kkA[i] = (g & 7) * 8;
  }
#pragma unroll
  for (int i = 0; i < 4; ++i) {
    int g = tid + i * 256;
    colB[i] = g >> 3; kkB[i] = (g & 7) * 8;
  }
  const float* abase[2];
#pragma unroll
  for (int i = 0; i < 2; ++i)
    abase[i] = emb + (size_t)(toks[rowA[i]] >> 14) * D + kkA[i];
  const unsigned short* bbase[4];
#pragma unroll
  for (int i = 0; i < 4; ++i)
    bbase[i] = pbD + (size_t)(c0 + colB[i]) * D + kkB[i];

  float4  arg[2][2][2];                     // [set][group][lo/hi]
  bf16x8  brg[2][4];                        // [set][group]

#define LOAD_SET(S_, K0_)                                                    \
  {                                                                          \
    _Pragma("unroll")                                                        \
    for (int i = 0; i < 2; ++i) {                                            \
      arg[S_][i][0] = *reinterpret_cast<const float4*>(abase[i] + (K0_));    \
      arg[S_][i][1] = *reinterpret_cast<const float4*>(abase[i] + (K0_) + 4);\
    }                                                                        \
    _Pragma("unroll")                                                        \
    for (int i = 0; i < 4; ++i)                                              \
      brg[S_][i] = *reinterpret_cast<const bf16x8*>(bbase[i] + (K0_));       \
  }

  LOAD_SET(0, 0)
  if (CHB > 1) LOAD_SET(1, 64)

  f32x4 acc[2][4];
#pragma unroll
  for (int fi = 0; fi < 2; ++fi)
#pragma unroll
    for (int fj = 0; fj < 4; ++fj) acc[fi][fj] = (f32x4){0.f, 0.f, 0.f, 0.f};

#pragma unroll
  for (int ch = 0; ch < CHB; ++ch) {
    const int cur = ch & 1;                 // compile-time after unroll
#pragma unroll
    for (int i = 0; i < 2; ++i) {
      bf16x8 o = pack8(arg[cur][i][0], arg[cur][i][1]);
      *reinterpret_cast<bf16x8*>(Ab + rowA[i] * 128 +
                                 ((kkA[i] * 2) ^ ((rowA[i] & 7) << 4))) = o;
    }
#pragma unroll
    for (int i = 0; i < 4; ++i)
      *reinterpret_cast<bf16x8*>(Bb + colB[i] * 128 +
                                 ((kkB[i] * 2) ^ ((colB[i] & 7) << 4))) = brg[cur][i];
    __syncthreads();

    if (ch + 2 < CHB) LOAD_SET(cur, (ch + 2) * 64)  // window ~1.5 chunks

#pragma unroll
    for (int s = 0; s < 2; ++s) {
      bf16x8 a[2], b[4];
#pragma unroll
      for (int fi = 0; fi < 2; ++fi) {
        int row = wr * 32 + fi * 16 + lr;
        a[fi] = *reinterpret_cast<const bf16x8*>(
            Ab + row * 128 + ((s * 64 + t16 * 16) ^ ((row & 7) << 4)));
      }
#pragma unroll
      for (int fj = 0; fj < 4; ++fj) {
        int col = wc * 64 + fj * 16 + lr;
        b[fj] = *reinterpret_cast<const bf16x8*>(
            Bb + col * 128 + ((s * 64 + t16 * 16) ^ ((col & 7) << 4)));
      }
#pragma unroll
      for (int fi = 0; fi < 2; ++fi)
#pragma unroll
        for (int fj = 0; fj < 4; ++fj)
          acc[fi][fj] = __builtin_amdgcn_mfma_f32_16x16x32_bf16(a[fi], b[fj], acc[fi][fj], 0, 0, 0);
    }
    __syncthreads();
  }
#undef LOAD_SET

  float* T = reinterpret_cast<float*>(smem + w * 4352);  // 16 rows x stride 68
#pragma unroll
  for (int fi = 0; fi < 2; ++fi) {
#pragma unroll
    for (int fj = 0; fj < 4; ++fj)
#pragma unroll
      for (int reg = 0; reg < 4; ++reg)
        T[(t16 * 4 + reg) * 68 + fj * 16 + lr] = acc[fi][fj][reg];
#pragma unroll
    for (int rr = 0; rr < 4; ++rr) {
      int p = wr * 32 + fi * 16 + rr * 4 + t16;
      if (r0 + p < cnt) {
        float4 v = *reinterpret_cast<const float4*>(&T[(rr * 4 + t16) * 68 + lr * 4]);
        *reinterpret_cast<float4*>(out + (size_t)(toks[p] & 16383u) * DPROJ +
                                   c0 + wc * 64 + lr * 4) = v;
      }
    }
  }
}

// ---------------------------------------------------------------------------
// Light path (D = 64 or 16): register-direct fragments; B from bf16 pb.
// [r16 verified]
// ---------------------------------------------------------------------------
template <int D>
__device__ __forceinline__ void gemm_light(const float* __restrict__ emb,
                                           const unsigned short* __restrict__ pbD,
                                           const unsigned* __restrict__ list,
                                           int cnt, int r0, int c0,
                                           float* __restrict__ out, char* smem) {
  constexpr int S = (D == 64) ? 2 : 1;
  const int tid  = threadIdx.x;
  const int lane = tid & 63;
  const int w    = tid >> 6;
  const int wr   = w >> 1, wc = w & 1;
  const int lr   = lane & 15, t16 = lane >> 4;

  unsigned* toks = (unsigned*)smem;
  if (tid < 64) {
    int p = r0 + tid;
    toks[tid] = (p < cnt) ? list[p] : 0u;
  }
  __syncthreads();

  bf16x8 a[2][S], b[4][S];
#pragma unroll
  for (int fi = 0; fi < 2; ++fi) {
    const float* eb = emb + (size_t)(toks[wr * 32 + fi * 16 + lr] >> 14) * D;
#pragma unroll
    for (int s = 0; s < S; ++s) {
      float4 lo = make_float4(0.f, 0.f, 0.f, 0.f), hi = lo;
      if (D == 64 || t16 < 2) {
        lo = *reinterpret_cast<const float4*>(eb + s * 32 + t16 * 8);
        hi = *reinterpret_cast<const float4*>(eb + s * 32 + t16 * 8 + 4);
      }
      a[fi][s] = pack8(lo, hi);
    }
  }
#pragma unroll
  for (int fj = 0; fj < 4; ++fj) {
    const unsigned short* pbc = pbD + (size_t)(c0 + wc * 64 + fj * 16 + lr) * D;
#pragma unroll
    for (int s = 0; s < S; ++s) {
      bf16x8 z = {0, 0, 0, 0, 0, 0, 0, 0};
      if (D == 64 || t16 < 2)
        z = *reinterpret_cast<const bf16x8*>(pbc + s * 32 + t16 * 8);
      b[fj][s] = z;
    }
  }

  f32x4 acc[2][4];
#pragma unroll
  for (int fi = 0; fi < 2; ++fi)
#pragma unroll
    for (int fj = 0; fj < 4; ++fj) acc[fi][fj] = (f32x4){0.f, 0.f, 0.f, 0.f};
#pragma unroll
  for (int s = 0; s < S; ++s)
#pragma unroll
    for (int fi = 0; fi < 2; ++fi)
#pragma unroll
      for (int fj = 0; fj < 4; ++fj)
        acc[fi][fj] = __builtin_amdgcn_mfma_f32_16x16x32_bf16(a[fi][s], b[fj][s], acc[fi][fj], 0, 0, 0);

  float* T = reinterpret_cast<float*>(smem + 256) + w * 1088;
#pragma unroll
  for (int fi = 0; fi < 2; ++fi) {
#pragma unroll
    for (int fj = 0; fj < 4; ++fj)
#pragma unroll
      for (int reg = 0; reg < 4; ++reg)
        T[(t16 * 4 + reg) * 68 + fj * 16 + lr] = acc[fi][fj][reg];
#pragma unroll
    for (int rr = 0; rr < 4; ++rr) {
      int p = wr * 32 + fi * 16 + rr * 4 + t16;
      if (r0 + p < cnt) {
        float4 v = *reinterpret_cast<const float4*>(&T[(rr * 4 + t16) * 68 + lr * 4]);
        *reinterpret_cast<float4*>(out + (size_t)(toks[p] & 16383u) * DPROJ +
                                   c0 + wc * 64 + lr * 4) = v;
      }
    }
  }
}

// ---------------------------------------------------------------------------
// Dispatcher: r16's XCD-grouping decode. tile t = ((bx>>6)<<3)+(bx&7) -> the
// 8 col-slices of a tile share an XCD, within a 64-id span. Heavy first.
// ---------------------------------------------------------------------------
__global__ __launch_bounds__(256) void gemm_all(
    const float* __restrict__ e0, const float* __restrict__ e1,
    const float* __restrict__ e2, const float* __restrict__ e3,
    const unsigned short* __restrict__ pb,
    const int* __restrict__ counts, const unsigned* __restrict__ lists,
    float* __restrict__ out, int n) {
  extern __shared__ char smem[];
  int bx = blockIdx.x;
  int t  = ((bx >> 6) << 3) + (bx & 7);
  int c0 = ((bx >> 3) & 7) * 128;
  int4 c = *reinterpret_cast<const int4*>(counts);
  int t0 = (c.x + 63) >> 6, t1 = (c.y + 63) >> 6,
      t2 = (c.z + 63) >> 6, t3 = (c.w + 63) >> 6;
  if (t < t0) { gemm_heavy<1024, 16>(e0, pb,           lists,               c.x, t * 64, c0, out, smem); return; }
  t -= t0;
  if (t < t1) { gemm_heavy< 256,  4>(e1, pb + 1048576, lists + (size_t)n,   c.y, t * 64, c0, out, smem); return; }
  t -= t1;
  if (t < t2) { gemm_light<64>(e2, pb + 1310720, lists + (size_t)2 * n, c.z, t * 64, c0, out, smem); return; }
  t -= t2;
  if (t < t3) { gemm_light<16>(e3, pb + 1376256, lists + (size_t)3 * n, c.w, t * 64, c0, out, smem); return; }
}

// ---------------------------------------------------------------------------
// Input order (setup_inputs dict order, verified rounds 1-17):
// inp, emb0, proj0, emb1, proj1, emb2, proj2, emb3, proj3.
// ws bytes: [0,16) counts | [1040,263184) lists | [524288, 3309568) pb bf16.
// ---------------------------------------------------------------------------
extern "C" void kernel_launch(void* const* d_in, const int* in_sizes, int n_in,
                              void* d_out, int out_size, void* d_ws, size_t ws_size,
                              hipStream_t stream) {
  const int*   inp   = (const int*)d_in[0];
  const float* emb0  = (const float*)d_in[1];
  const float* proj0 = (const float*)d_in[2];
  const float* emb1  = (const float*)d_in[3];
  const float* proj1 = (const float*)d_in[4];
  const float* emb2  = (const float*)d_in[5];
  const float* proj2 = (const float*)d_in[6];
  const float* emb3  = (const float*)d_in[7];
  const float* proj3 = (const float*)d_in[8];
  float* out = (float*)d_out;
  const int n = in_sizes[0];  // 16384 tokens

  int*            counts = (int*)d_ws;
  unsigned*       lists  = (unsigned*)d_ws + 260;
  unsigned short* pb     = (unsigned short*)((char*)d_ws + 524288);

  const int nb = (n + 255) / 256;           // 64
  prep<<<dim3(680), dim3(256), 0, stream>>>(proj0, proj1, proj2, proj3, pb,
                                            inp, n, nb, lists, counts);

  // tiles: sum_i ceil(cnt_i/64) <= n/64 + 3 = 259; pad to 264 (multiple of 8).
  dim3 grid(264 * 8, 1, 1);
  size_t smem_bytes = 24576 + 64 * sizeof(unsigned);  // 24832 B -> 6 blocks/CU
  gemm_all<<<grid, dim3(256), smem_bytes, stream>>>(emb0, emb1, emb2, emb3, pb,
                                                    counts, lists, out, n);
}

// Round 19
// 38.402 us; speedup vs baseline: 1.3849x; 1.3849x over previous
//
#include <hip/hip_runtime.h>

#define DPROJ 1024

typedef short  bf16x8 __attribute__((ext_vector_type(8)));
typedef float  f32x4  __attribute__((ext_vector_type(4)));

__device__ __forceinline__ unsigned short f2bf(float f) {
  unsigned u = __builtin_bit_cast(unsigned, f);
  u += 0x7FFFu + ((u >> 16) & 1u);          // round-to-nearest-even
  return (unsigned short)(u >> 16);
}

__device__ __forceinline__ bf16x8 pack8(float4 lo, float4 hi) {
  bf16x8 r;
  r[0] = (short)f2bf(lo.x); r[1] = (short)f2bf(lo.y);
  r[2] = (short)f2bf(lo.z); r[3] = (short)f2bf(lo.w);
  r[4] = (short)f2bf(hi.x); r[5] = (short)f2bf(hi.y);
  r[6] = (short)f2bf(hi.z); r[7] = (short)f2bf(hi.w);
  return r;
}

__device__ __forceinline__ int bucket_of(int v) {
  return (v >= 200000) ? 3 : (v >= 40000) ? 2 : (v >= 20000) ? 1 : 0;
}

// ---------------------------------------------------------------------------
// Kernel 1: fused proj fp32->bf16 conversion (680 blocks) + per-block bucket
// counts (first nb blocks). pb elem offsets: p0 @0, p1 @1048576, p2 @1310720,
// p3 @1376256; total 1392640 elems (2.72 MB -> L2/L3 resident). [r16 verified]
// ---------------------------------------------------------------------------
__global__ __launch_bounds__(256) void convert_count(
    const float* __restrict__ p0, const float* __restrict__ p1,
    const float* __restrict__ p2, const float* __restrict__ p3,
    unsigned short* __restrict__ pb,
    const int* __restrict__ inp, int n, int nb, int* __restrict__ blkcnt) {
  size_t base = ((size_t)blockIdx.x * 256 + threadIdx.x) * 8;
  if (base < 1392640u) {
    const float* src;
    if      (base < 1048576u) src = p0 + base;
    else if (base < 1310720u) src = p1 + (base - 1048576u);
    else if (base < 1376256u) src = p2 + (base - 1310720u);
    else                      src = p3 + (base - 1376256u);
    float4 lo = reinterpret_cast<const float4*>(src)[0];
    float4 hi = reinterpret_cast<const float4*>(src)[1];
    *reinterpret_cast<bf16x8*>(pb + base) = pack8(lo, hi);
  }
  if (blockIdx.x < (unsigned)nb) {
    int t = blockIdx.x * 256 + threadIdx.x;
    int lane = threadIdx.x & 63, w = threadIdx.x >> 6;
    int v = (t < n) ? inp[t] : -1;
    int b = (v < 0) ? -1 : bucket_of(v);
    __shared__ int cnt[4][4];
#pragma unroll
    for (int i = 0; i < 4; ++i) {
      unsigned long long m = __ballot(b == i);
      if (lane == 0) cnt[w][i] = __popcll(m);
    }
    __syncthreads();
    if (threadIdx.x < 4) {
      int s = cnt[0][threadIdx.x] + cnt[1][threadIdx.x] +
              cnt[2][threadIdx.x] + cnt[3][threadIdx.x];
      blkcnt[blockIdx.x * 4 + threadIdx.x] = s;
    }
  }
}

// ---------------------------------------------------------------------------
// Kernel 2: scatter with inline scan. Token-ascending lists. [r16 verified]
// Entry packs (in-bucket row << 14) | token_id  (n = 16384 = 2^14).
// ---------------------------------------------------------------------------
__global__ __launch_bounds__(256) void scatter_kernel(const int* __restrict__ inp, int n,
                                                      const int* __restrict__ blkcnt, int nb,
                                                      unsigned* __restrict__ lists,
                                                      int* __restrict__ counts) {
  int t = blockIdx.x * 256 + threadIdx.x;
  int lane = threadIdx.x & 63, w = threadIdx.x >> 6;
  __shared__ int cnt[4][4];
  __shared__ int off_s[4];
  {
    int sv = (lane < nb) ? blkcnt[lane * 4 + w] : 0;
    int x = sv;
#pragma unroll
    for (int d = 1; d < 64; d <<= 1) {
      int y = __shfl_up(x, d);
      if (lane >= d) x += y;
    }
    int myoff = __shfl(x - sv, blockIdx.x);
    if (lane == 0) off_s[w] = myoff;
    if (blockIdx.x == 0 && lane == 63) counts[w] = x;
  }
  int v = (t < n) ? inp[t] : -1;
  int b = (v < 0) ? -1 : bucket_of(v);
  int lo = (b == 3) ? 200000 : (b == 2) ? 40000 : (b == 1) ? 20000 : 0;
  int myrank = 0;
#pragma unroll
  for (int i = 0; i < 4; ++i) {
    unsigned long long m = __ballot(b == i);
    if (lane == 0) cnt[w][i] = __popcll(m);
    if (b == i) myrank = __popcll(m & ((1ull << lane) - 1ull));
  }
  __syncthreads();
  if (b >= 0) {
    int prefix = 0;
    for (int w2 = 0; w2 < w; ++w2) prefix += cnt[w2][b];
    int pos = off_s[b] + prefix + myrank;
    lists[(size_t)b * n + pos] = ((unsigned)(v - lo) << 14) | (unsigned)t;
  }
}

// ---------------------------------------------------------------------------
// Heavy path: full-K (CHB chunks). Prefetch DISTANCE 3 (three static register
// sets; loop fully unrolled -> ch%3 folds to compile-time constants). Reload
// for chunk ch+3 is issued after chunk ch's barrier -> in flight across ~2.5
// chunks (~700+ cycles), covering the random-row emb gather latency that
// distance-2 left exposed. A gathered fp32 (converted in staging); B direct
// bf16 from L2-resident pb. LDS XOR swizzle byte ^= (row&7)<<4 (G4).
// ---------------------------------------------------------------------------
template <int D, int CHB>
__device__ __forceinline__ void gemm_heavy(const float* __restrict__ emb,
                                           const unsigned short* __restrict__ pbD,
                                           const unsigned* __restrict__ list,
                                           int cnt, int r0, int c0,
                                           float* __restrict__ out, char* smem) {
  const int tid  = threadIdx.x;
  const int lane = tid & 63;
  const int w    = tid >> 6;
  const int wr   = w >> 1, wc = w & 1;     // 2x2 wave grid: 32 rows x 64 cols
  const int lr   = lane & 15, t16 = lane >> 4;

  char* Ab = smem;                          // A: 64 rows x 128 B  =  8 KB
  char* Bb = smem + 8192;                   // B: 128 cols x 128 B = 16 KB
  unsigned* toks = (unsigned*)(smem + 24576);

  if (tid < 64) {
    int p = r0 + tid;
    toks[tid] = (p < cnt) ? list[p] : 0u;   // pads -> row 0 (stores suppressed)
  }
  __syncthreads();

  int rowA[2], kkA[2], colB[4], kkB[4];
#pragma unroll
  for (int i = 0; i < 2; ++i) {
    int g = tid + i * 256;
    rowA[i] = g >> 3; kkA[i] = (g & 7) * 8;
  }
#pragma unroll
  for (int i = 0; i < 4; ++i) {
    int g = tid + i * 256;
    colB[i] = g >> 3; kkB[i] = (g & 7) * 8;
  }
  const float* abase[2];
#pragma unroll
  for (int i = 0; i < 2; ++i)
    abase[i] = emb + (size_t)(toks[rowA[i]] >> 14) * D + kkA[i];
  const unsigned short* bbase[4];
#pragma unroll
  for (int i = 0; i < 4; ++i)
    bbase[i] = pbD + (size_t)(c0 + colB[i]) * D + kkB[i];

  float4  arg[3][2][2];                     // [set][group][lo/hi]
  bf16x8  brg[3][4];                        // [set][group]

#define LOAD_SET(S_, K0_)                                                    \
  {                                                                          \
    _Pragma("unroll")                                                        \
    for (int i = 0; i < 2; ++i) {                                            \
      arg[S_][i][0] = *reinterpret_cast<const float4*>(abase[i] + (K0_));    \
      arg[S_][i][1] = *reinterpret_cast<const float4*>(abase[i] + (K0_) + 4);\
    }                                                                        \
    _Pragma("unroll")                                                        \
    for (int i = 0; i < 4; ++i)                                              \
      brg[S_][i] = *reinterpret_cast<const bf16x8*>(bbase[i] + (K0_));       \
  }

  LOAD_SET(0, 0)
  if (CHB > 1) LOAD_SET(1, 64)
  if (CHB > 2) LOAD_SET(2, 128)

  f32x4 acc[2][4];
#pragma unroll
  for (int fi = 0; fi < 2; ++fi)
#pragma unroll
    for (int fj = 0; fj < 4; ++fj) acc[fi][fj] = (f32x4){0.f, 0.f, 0.f, 0.f};

#pragma unroll
  for (int ch = 0; ch < CHB; ++ch) {
    const int cur = ch % 3;                 // compile-time after full unroll
#pragma unroll
    for (int i = 0; i < 2; ++i) {
      bf16x8 o = pack8(arg[cur][i][0], arg[cur][i][1]);
      *reinterpret_cast<bf16x8*>(Ab + rowA[i] * 128 +
                                 ((kkA[i] * 2) ^ ((rowA[i] & 7) << 4))) = o;
    }
#pragma unroll
    for (int i = 0; i < 4; ++i)
      *reinterpret_cast<bf16x8*>(Bb + colB[i] * 128 +
                                 ((kkB[i] * 2) ^ ((colB[i] & 7) << 4))) = brg[cur][i];
    __syncthreads();

    if (ch + 3 < CHB) LOAD_SET(cur, (ch + 3) * 64)  // window ~2.5 chunks

#pragma unroll
    for (int s = 0; s < 2; ++s) {
      bf16x8 a[2], b[4];
#pragma unroll
      for (int fi = 0; fi < 2; ++fi) {
        int row = wr * 32 + fi * 16 + lr;
        a[fi] = *reinterpret_cast<const bf16x8*>(
            Ab + row * 128 + ((s * 64 + t16 * 16) ^ ((row & 7) << 4)));
      }
#pragma unroll
      for (int fj = 0; fj < 4; ++fj) {
        int col = wc * 64 + fj * 16 + lr;
        b[fj] = *reinterpret_cast<const bf16x8*>(
            Bb + col * 128 + ((s * 64 + t16 * 16) ^ ((col & 7) << 4)));
      }
#pragma unroll
      for (int fi = 0; fi < 2; ++fi)
#pragma unroll
        for (int fj = 0; fj < 4; ++fj)
          acc[fi][fj] = __builtin_amdgcn_mfma_f32_16x16x32_bf16(a[fi], b[fj], acc[fi][fj], 0, 0, 0);
    }
    __syncthreads();
  }
#undef LOAD_SET

  float* T = reinterpret_cast<float*>(smem + w * 4352);  // 16 rows x stride 68
#pragma unroll
  for (int fi = 0; fi < 2; ++fi) {
#pragma unroll
    for (int fj = 0; fj < 4; ++fj)
#pragma unroll
      for (int reg = 0; reg < 4; ++reg)
        T[(t16 * 4 + reg) * 68 + fj * 16 + lr] = acc[fi][fj][reg];
#pragma unroll
    for (int rr = 0; rr < 4; ++rr) {
      int p = wr * 32 + fi * 16 + rr * 4 + t16;
      if (r0 + p < cnt) {
        float4 v = *reinterpret_cast<const float4*>(&T[(rr * 4 + t16) * 68 + lr * 4]);
        *reinterpret_cast<float4*>(out + (size_t)(toks[p] & 16383u) * DPROJ +
                                   c0 + wc * 64 + lr * 4) = v;
      }
    }
  }
}

// ---------------------------------------------------------------------------
// Light path (D = 64 or 16): register-direct fragments; B from bf16 pb.
// [r16 verified]
// ---------------------------------------------------------------------------
template <int D>
__device__ __forceinline__ void gemm_light(const float* __restrict__ emb,
                                           const unsigned short* __restrict__ pbD,
                                           const unsigned* __restrict__ list,
                                           int cnt, int r0, int c0,
                                           float* __restrict__ out, char* smem) {
  constexpr int S = (D == 64) ? 2 : 1;
  const int tid  = threadIdx.x;
  const int lane = tid & 63;
  const int w    = tid >> 6;
  const int wr   = w >> 1, wc = w & 1;
  const int lr   = lane & 15, t16 = lane >> 4;

  unsigned* toks = (unsigned*)smem;
  if (tid < 64) {
    int p = r0 + tid;
    toks[tid] = (p < cnt) ? list[p] : 0u;
  }
  __syncthreads();

  bf16x8 a[2][S], b[4][S];
#pragma unroll
  for (int fi = 0; fi < 2; ++fi) {
    const float* eb = emb + (size_t)(toks[wr * 32 + fi * 16 + lr] >> 14) * D;
#pragma unroll
    for (int s = 0; s < S; ++s) {
      float4 lo = make_float4(0.f, 0.f, 0.f, 0.f), hi = lo;
      if (D == 64 || t16 < 2) {
        lo = *reinterpret_cast<const float4*>(eb + s * 32 + t16 * 8);
        hi = *reinterpret_cast<const float4*>(eb + s * 32 + t16 * 8 + 4);
      }
      a[fi][s] = pack8(lo, hi);
    }
  }
#pragma unroll
  for (int fj = 0; fj < 4; ++fj) {
    const unsigned short* pbc = pbD + (size_t)(c0 + wc * 64 + fj * 16 + lr) * D;
#pragma unroll
    for (int s = 0; s < S; ++s) {
      bf16x8 z = {0, 0, 0, 0, 0, 0, 0, 0};
      if (D == 64 || t16 < 2)
        z = *reinterpret_cast<const bf16x8*>(pbc + s * 32 + t16 * 8);
      b[fj][s] = z;
    }
  }

  f32x4 acc[2][4];
#pragma unroll
  for (int fi = 0; fi < 2; ++fi)
#pragma unroll
    for (int fj = 0; fj < 4; ++fj) acc[fi][fj] = (f32x4){0.f, 0.f, 0.f, 0.f};
#pragma unroll
  for (int s = 0; s < S; ++s)
#pragma unroll
    for (int fi = 0; fi < 2; ++fi)
#pragma unroll
      for (int fj = 0; fj < 4; ++fj)
        acc[fi][fj] = __builtin_amdgcn_mfma_f32_16x16x32_bf16(a[fi][s], b[fj][s], acc[fi][fj], 0, 0, 0);

  float* T = reinterpret_cast<float*>(smem + 256) + w * 1088;
#pragma unroll
  for (int fi = 0; fi < 2; ++fi) {
#pragma unroll
    for (int fj = 0; fj < 4; ++fj)
#pragma unroll
      for (int reg = 0; reg < 4; ++reg)
        T[(t16 * 4 + reg) * 68 + fj * 16 + lr] = acc[fi][fj][reg];
#pragma unroll
    for (int rr = 0; rr < 4; ++rr) {
      int p = wr * 32 + fi * 16 + rr * 4 + t16;
      if (r0 + p < cnt) {
        float4 v = *reinterpret_cast<const float4*>(&T[(rr * 4 + t16) * 68 + lr * 4]);
        *reinterpret_cast<float4*>(out + (size_t)(toks[p] & 16383u) * DPROJ +
                                   c0 + wc * 64 + lr * 4) = v;
      }
    }
  }
}

// ---------------------------------------------------------------------------
// Dispatcher: r16's XCD-grouping decode. tile t = ((bx>>6)<<3)+(bx&7) -> the
// 8 col-slices of a tile share an XCD, within a 64-id span. Heavy first.
// ---------------------------------------------------------------------------
__global__ __launch_bounds__(256) void gemm_all(
    const float* __restrict__ e0, const float* __restrict__ e1,
    const float* __restrict__ e2, const float* __restrict__ e3,
    const unsigned short* __restrict__ pb,
    const int* __restrict__ counts, const unsigned* __restrict__ lists,
    float* __restrict__ out, int n) {
  extern __shared__ char smem[];
  int bx = blockIdx.x;
  int t  = ((bx >> 6) << 3) + (bx & 7);
  int c0 = ((bx >> 3) & 7) * 128;
  int4 c = *reinterpret_cast<const int4*>(counts);
  int t0 = (c.x + 63) >> 6, t1 = (c.y + 63) >> 6,
      t2 = (c.z + 63) >> 6, t3 = (c.w + 63) >> 6;
  if (t < t0) { gemm_heavy<1024, 16>(e0, pb,           lists,               c.x, t * 64, c0, out, smem); return; }
  t -= t0;
  if (t < t1) { gemm_heavy< 256,  4>(e1, pb + 1048576, lists + (size_t)n,   c.y, t * 64, c0, out, smem); return; }
  t -= t1;
  if (t < t2) { gemm_light<64>(e2, pb + 1310720, lists + (size_t)2 * n, c.z, t * 64, c0, out, smem); return; }
  t -= t2;
  if (t < t3) { gemm_light<16>(e3, pb + 1376256, lists + (size_t)3 * n, c.w, t * 64, c0, out, smem); return; }
}

// ---------------------------------------------------------------------------
// Input order (setup_inputs dict order, verified rounds 1-18):
// inp, emb0, proj0, emb1, proj1, emb2, proj2, emb3, proj3.
// ws bytes: [0,16) counts | [16,1040) blkcnt | [1040,263184) lists |
// [524288, 3309568) pb bf16.
// ---------------------------------------------------------------------------
extern "C" void kernel_launch(void* const* d_in, const int* in_sizes, int n_in,
                              void* d_out, int out_size, void* d_ws, size_t ws_size,
                              hipStream_t stream) {
  const int*   inp   = (const int*)d_in[0];
  const float* emb0  = (const float*)d_in[1];
  const float* proj0 = (const float*)d_in[2];
  const float* emb1  = (const float*)d_in[3];
  const float* proj1 = (const float*)d_in[4];
  const float* emb2  = (const float*)d_in[5];
  const float* proj2 = (const float*)d_in[6];
  const float* emb3  = (const float*)d_in[7];
  const float* proj3 = (const float*)d_in[8];
  float* out = (float*)d_out;
  const int n = in_sizes[0];  // 16384 tokens

  int*            counts = (int*)d_ws;
  int*            blkcnt = (int*)d_ws + 4;
  unsigned*       lists  = (unsigned*)d_ws + 260;
  unsigned short* pb     = (unsigned short*)((char*)d_ws + 524288);

  const int nb = (n + 255) / 256;           // 64 (scan supports <= 64)
  convert_count<<<dim3(680), dim3(256), 0, stream>>>(proj0, proj1, proj2, proj3,
                                                     pb, inp, n, nb, blkcnt);
  scatter_kernel<<<dim3(nb), dim3(256), 0, stream>>>(inp, n, blkcnt, nb, lists, counts);

  // tiles: sum_i ceil(cnt_i/64) <= n/64 + 3 = 259; pad to 264 (multiple of 8).
  dim3 grid(264 * 8, 1, 1);
  size_t smem_bytes = 24576 + 64 * sizeof(unsigned);  // 24832 B -> 6 blocks/CU
  gemm_all<<<grid, dim3(256), smem_bytes, stream>>>(emb0, emb1, emb2, emb3, pb,
                                                    counts, lists, out, n);
}

// Round 20
// 35.706 us; speedup vs baseline: 1.4894x; 1.0755x over previous
//
#include <hip/hip_runtime.h>

#define DPROJ 1024

typedef short  bf16x8 __attribute__((ext_vector_type(8)));
typedef float  f32x4  __attribute__((ext_vector_type(4)));

__device__ __forceinline__ unsigned short f2bf(float f) {
  unsigned u = __builtin_bit_cast(unsigned, f);
  u += 0x7FFFu + ((u >> 16) & 1u);          // round-to-nearest-even
  return (unsigned short)(u >> 16);
}

__device__ __forceinline__ bf16x8 pack8(float4 lo, float4 hi) {
  bf16x8 r;
  r[0] = (short)f2bf(lo.x); r[1] = (short)f2bf(lo.y);
  r[2] = (short)f2bf(lo.z); r[3] = (short)f2bf(lo.w);
  r[4] = (short)f2bf(hi.x); r[5] = (short)f2bf(hi.y);
  r[6] = (short)f2bf(hi.z); r[7] = (short)f2bf(hi.w);
  return r;
}

__device__ __forceinline__ int bucket_of(int v) {
  return (v >= 200000) ? 3 : (v >= 40000) ? 2 : (v >= 20000) ? 1 : 0;
}

// ---------------------------------------------------------------------------
// Kernel 1: fused proj fp32->bf16 conversion (680 blocks) + per-block bucket
// counts (first nb blocks). pb elem offsets: p0 @0, p1 @1048576, p2 @1310720,
// p3 @1376256; total 1392640 elems (2.72 MB -> L2/L3 resident). [r16 verified]
// ---------------------------------------------------------------------------
__global__ __launch_bounds__(256) void convert_count(
    const float* __restrict__ p0, const float* __restrict__ p1,
    const float* __restrict__ p2, const float* __restrict__ p3,
    unsigned short* __restrict__ pb,
    const int* __restrict__ inp, int n, int nb, int* __restrict__ blkcnt) {
  size_t base = ((size_t)blockIdx.x * 256 + threadIdx.x) * 8;
  if (base < 1392640u) {
    const float* src;
    if      (base < 1048576u) src = p0 + base;
    else if (base < 1310720u) src = p1 + (base - 1048576u);
    else if (base < 1376256u) src = p2 + (base - 1310720u);
    else                      src = p3 + (base - 1376256u);
    float4 lo = reinterpret_cast<const float4*>(src)[0];
    float4 hi = reinterpret_cast<const float4*>(src)[1];
    *reinterpret_cast<bf16x8*>(pb + base) = pack8(lo, hi);
  }
  if (blockIdx.x < (unsigned)nb) {
    int t = blockIdx.x * 256 + threadIdx.x;
    int lane = threadIdx.x & 63, w = threadIdx.x >> 6;
    int v = (t < n) ? inp[t] : -1;
    int b = (v < 0) ? -1 : bucket_of(v);
    __shared__ int cnt[4][4];
#pragma unroll
    for (int i = 0; i < 4; ++i) {
      unsigned long long m = __ballot(b == i);
      if (lane == 0) cnt[w][i] = __popcll(m);
    }
    __syncthreads();
    if (threadIdx.x < 4) {
      int s = cnt[0][threadIdx.x] + cnt[1][threadIdx.x] +
              cnt[2][threadIdx.x] + cnt[3][threadIdx.x];
      blkcnt[blockIdx.x * 4 + threadIdx.x] = s;
    }
  }
}

// ---------------------------------------------------------------------------
// Kernel 2: scatter with inline scan. Token-ascending lists. [r16 verified]
// Entry packs (in-bucket row << 14) | token_id  (n = 16384 = 2^14).
// ---------------------------------------------------------------------------
__global__ __launch_bounds__(256) void scatter_kernel(const int* __restrict__ inp, int n,
                                                      const int* __restrict__ blkcnt, int nb,
                                                      unsigned* __restrict__ lists,
                                                      int* __restrict__ counts) {
  int t = blockIdx.x * 256 + threadIdx.x;
  int lane = threadIdx.x & 63, w = threadIdx.x >> 6;
  __shared__ int cnt[4][4];
  __shared__ int off_s[4];
  {
    int sv = (lane < nb) ? blkcnt[lane * 4 + w] : 0;
    int x = sv;
#pragma unroll
    for (int d = 1; d < 64; d <<= 1) {
      int y = __shfl_up(x, d);
      if (lane >= d) x += y;
    }
    int myoff = __shfl(x - sv, blockIdx.x);
    if (lane == 0) off_s[w] = myoff;
    if (blockIdx.x == 0 && lane == 63) counts[w] = x;
  }
  int v = (t < n) ? inp[t] : -1;
  int b = (v < 0) ? -1 : bucket_of(v);
  int lo = (b == 3) ? 200000 : (b == 2) ? 40000 : (b == 1) ? 20000 : 0;
  int myrank = 0;
#pragma unroll
  for (int i = 0; i < 4; ++i) {
    unsigned long long m = __ballot(b == i);
    if (lane == 0) cnt[w][i] = __popcll(m);
    if (b == i) myrank = __popcll(m & ((1ull << lane) - 1ull));
  }
  __syncthreads();
  if (b >= 0) {
    int prefix = 0;
    for (int w2 = 0; w2 < w; ++w2) prefix += cnt[w2][b];
    int pos = off_s[b] + prefix + myrank;
    lists[(size_t)b * n + pos] = ((unsigned)(v - lo) << 14) | (unsigned)t;
  }
}

// ---------------------------------------------------------------------------
// Heavy path: full-K (CHB chunks). Prefetch DISTANCE 2 (two static register
// sets, loop fully unrolled -> compile-time set indices). A gathered from
// fp32 emb (converted in staging); B direct bf16 from L2-resident pb (no
// conversion VALU, half bytes). LDS XOR swizzle byte ^= (row&7)<<4 (G4).
// [r16 verified, 35.5 us config]
// ---------------------------------------------------------------------------
template <int D, int CHB>
__device__ __forceinline__ void gemm_heavy(const float* __restrict__ emb,
                                           const unsigned short* __restrict__ pbD,
                                           const unsigned* __restrict__ list,
                                           int cnt, int r0, int c0,
                                           float* __restrict__ out, char* smem) {
  const int tid  = threadIdx.x;
  const int lane = tid & 63;
  const int w    = tid >> 6;
  const int wr   = w >> 1, wc = w & 1;     // 2x2 wave grid: 32 rows x 64 cols
  const int lr   = lane & 15, t16 = lane >> 4;

  char* Ab = smem;                          // A: 64 rows x 128 B  =  8 KB
  char* Bb = smem + 8192;                   // B: 128 cols x 128 B = 16 KB
  unsigned* toks = (unsigned*)(smem + 24576);

  if (tid < 64) {
    int p = r0 + tid;
    toks[tid] = (p < cnt) ? list[p] : 0u;   // pads -> row 0 (stores suppressed)
  }
  __syncthreads();

  int rowA[2], kkA[2], colB[4], kkB[4];
#pragma unroll
  for (int i = 0; i < 2; ++i) {
    int g = tid + i * 256;
    rowA[i] = g >> 3; kkA[i] = (g & 7) * 8;
  }
#pragma unroll
  for (int i = 0; i < 4; ++i) {
    int g = tid + i * 256;
    colB[i] = g >> 3; kkB[i] = (g & 7) * 8;
  }
  const float* abase[2];
#pragma unroll
  for (int i = 0; i < 2; ++i)
    abase[i] = emb + (size_t)(toks[rowA[i]] >> 14) * D + kkA[i];
  const unsigned short* bbase[4];
#pragma unroll
  for (int i = 0; i < 4; ++i)
    bbase[i] = pbD + (size_t)(c0 + colB[i]) * D + kkB[i];

  float4  arg[2][2][2];                     // [set][group][lo/hi]
  bf16x8  brg[2][4];                        // [set][group]

#define LOAD_SET(S_, K0_)                                                    \
  {                                                                          \
    _Pragma("unroll")                                                        \
    for (int i = 0; i < 2; ++i) {                                            \
      arg[S_][i][0] = *reinterpret_cast<const float4*>(abase[i] + (K0_));    \
      arg[S_][i][1] = *reinterpret_cast<const float4*>(abase[i] + (K0_) + 4);\
    }                                                                        \
    _Pragma("unroll")                                                        \
    for (int i = 0; i < 4; ++i)                                              \
      brg[S_][i] = *reinterpret_cast<const bf16x8*>(bbase[i] + (K0_));       \
  }

  LOAD_SET(0, 0)
  if (CHB > 1) LOAD_SET(1, 64)

  f32x4 acc[2][4];
#pragma unroll
  for (int fi = 0; fi < 2; ++fi)
#pragma unroll
    for (int fj = 0; fj < 4; ++fj) acc[fi][fj] = (f32x4){0.f, 0.f, 0.f, 0.f};

#pragma unroll
  for (int ch = 0; ch < CHB; ++ch) {
    const int cur = ch & 1;                 // compile-time after unroll
#pragma unroll
    for (int i = 0; i < 2; ++i) {
      bf16x8 o = pack8(arg[cur][i][0], arg[cur][i][1]);
      *reinterpret_cast<bf16x8*>(Ab + rowA[i] * 128 +
                                 ((kkA[i] * 2) ^ ((rowA[i] & 7) << 4))) = o;
    }
#pragma unroll
    for (int i = 0; i < 4; ++i)
      *reinterpret_cast<bf16x8*>(Bb + colB[i] * 128 +
                                 ((kkB[i] * 2) ^ ((colB[i] & 7) << 4))) = brg[cur][i];
    __syncthreads();

    if (ch + 2 < CHB) LOAD_SET(cur, (ch + 2) * 64)  // window ~1.5 chunks

#pragma unroll
    for (int s = 0; s < 2; ++s) {
      bf16x8 a[2], b[4];
#pragma unroll
      for (int fi = 0; fi < 2; ++fi) {
        int row = wr * 32 + fi * 16 + lr;
        a[fi] = *reinterpret_cast<const bf16x8*>(
            Ab + row * 128 + ((s * 64 + t16 * 16) ^ ((row & 7) << 4)));
      }
#pragma unroll
      for (int fj = 0; fj < 4; ++fj) {
        int col = wc * 64 + fj * 16 + lr;
        b[fj] = *reinterpret_cast<const bf16x8*>(
            Bb + col * 128 + ((s * 64 + t16 * 16) ^ ((col & 7) << 4)));
      }
#pragma unroll
      for (int fi = 0; fi < 2; ++fi)
#pragma unroll
        for (int fj = 0; fj < 4; ++fj)
          acc[fi][fj] = __builtin_amdgcn_mfma_f32_16x16x32_bf16(a[fi], b[fj], acc[fi][fj], 0, 0, 0);
    }
    __syncthreads();
  }
#undef LOAD_SET

  float* T = reinterpret_cast<float*>(smem + w * 4352);  // 16 rows x stride 68
#pragma unroll
  for (int fi = 0; fi < 2; ++fi) {
#pragma unroll
    for (int fj = 0; fj < 4; ++fj)
#pragma unroll
      for (int reg = 0; reg < 4; ++reg)
        T[(t16 * 4 + reg) * 68 + fj * 16 + lr] = acc[fi][fj][reg];
#pragma unroll
    for (int rr = 0; rr < 4; ++rr) {
      int p = wr * 32 + fi * 16 + rr * 4 + t16;
      if (r0 + p < cnt) {
        float4 v = *reinterpret_cast<const float4*>(&T[(rr * 4 + t16) * 68 + lr * 4]);
        *reinterpret_cast<float4*>(out + (size_t)(toks[p] & 16383u) * DPROJ +
                                   c0 + wc * 64 + lr * 4) = v;
      }
    }
  }
}

// ---------------------------------------------------------------------------
// Light path (D = 64 or 16): register-direct fragments; B from bf16 pb.
// [r16 verified]
// ---------------------------------------------------------------------------
template <int D>
__device__ __forceinline__ void gemm_light(const float* __restrict__ emb,
                                           const unsigned short* __restrict__ pbD,
                                           const unsigned* __restrict__ list,
                                           int cnt, int r0, int c0,
                                           float* __restrict__ out, char* smem) {
  constexpr int S = (D == 64) ? 2 : 1;
  const int tid  = threadIdx.x;
  const int lane = tid & 63;
  const int w    = tid >> 6;
  const int wr   = w >> 1, wc = w & 1;
  const int lr   = lane & 15, t16 = lane >> 4;

  unsigned* toks = (unsigned*)smem;
  if (tid < 64) {
    int p = r0 + tid;
    toks[tid] = (p < cnt) ? list[p] : 0u;
  }
  __syncthreads();

  bf16x8 a[2][S], b[4][S];
#pragma unroll
  for (int fi = 0; fi < 2; ++fi) {
    const float* eb = emb + (size_t)(toks[wr * 32 + fi * 16 + lr] >> 14) * D;
#pragma unroll
    for (int s = 0; s < S; ++s) {
      float4 lo = make_float4(0.f, 0.f, 0.f, 0.f), hi = lo;
      if (D == 64 || t16 < 2) {
        lo = *reinterpret_cast<const float4*>(eb + s * 32 + t16 * 8);
        hi = *reinterpret_cast<const float4*>(eb + s * 32 + t16 * 8 + 4);
      }
      a[fi][s] = pack8(lo, hi);
    }
  }
#pragma unroll
  for (int fj = 0; fj < 4; ++fj) {
    const unsigned short* pbc = pbD + (size_t)(c0 + wc * 64 + fj * 16 + lr) * D;
#pragma unroll
    for (int s = 0; s < S; ++s) {
      bf16x8 z = {0, 0, 0, 0, 0, 0, 0, 0};
      if (D == 64 || t16 < 2)
        z = *reinterpret_cast<const bf16x8*>(pbc + s * 32 + t16 * 8);
      b[fj][s] = z;
    }
  }

  f32x4 acc[2][4];
#pragma unroll
  for (int fi = 0; fi < 2; ++fi)
#pragma unroll
    for (int fj = 0; fj < 4; ++fj) acc[fi][fj] = (f32x4){0.f, 0.f, 0.f, 0.f};
#pragma unroll
  for (int s = 0; s < S; ++s)
#pragma unroll
    for (int fi = 0; fi < 2; ++fi)
#pragma unroll
      for (int fj = 0; fj < 4; ++fj)
        acc[fi][fj] = __builtin_amdgcn_mfma_f32_16x16x32_bf16(a[fi][s], b[fj][s], acc[fi][fj], 0, 0, 0);

  float* T = reinterpret_cast<float*>(smem + 256) + w * 1088;
#pragma unroll
  for (int fi = 0; fi < 2; ++fi) {
#pragma unroll
    for (int fj = 0; fj < 4; ++fj)
#pragma unroll
      for (int reg = 0; reg < 4; ++reg)
        T[(t16 * 4 + reg) * 68 + fj * 16 + lr] = acc[fi][fj][reg];
#pragma unroll
    for (int rr = 0; rr < 4; ++rr) {
      int p = wr * 32 + fi * 16 + rr * 4 + t16;
      if (r0 + p < cnt) {
        float4 v = *reinterpret_cast<const float4*>(&T[(rr * 4 + t16) * 68 + lr * 4]);
        *reinterpret_cast<float4*>(out + (size_t)(toks[p] & 16383u) * DPROJ +
                                   c0 + wc * 64 + lr * 4) = v;
      }
    }
  }
}

// ---------------------------------------------------------------------------
// Dispatcher: r12's XCD-grouping decode (best config). tile t = ((bx>>6)<<3)
// + (bx&7) -> the 8 col-slices of a tile have ids base+8c: same XCD, within
// a 64-id span. Heavy tiles first. Full-K b0 (no split-K).
// ---------------------------------------------------------------------------
__global__ __launch_bounds__(256) void gemm_all(
    const float* __restrict__ e0, const float* __restrict__ e1,
    const float* __restrict__ e2, const float* __restrict__ e3,
    const unsigned short* __restrict__ pb,
    const int* __restrict__ counts, const unsigned* __restrict__ lists,
    float* __restrict__ out, int n) {
  extern __shared__ char smem[];
  int bx = blockIdx.x;
  int t  = ((bx >> 6) << 3) + (bx & 7);
  int c0 = ((bx >> 3) & 7) * 128;
  int4 c = *reinterpret_cast<const int4*>(counts);
  int t0 = (c.x + 63) >> 6, t1 = (c.y + 63) >> 6,
      t2 = (c.z + 63) >> 6, t3 = (c.w + 63) >> 6;
  if (t < t0) { gemm_heavy<1024, 16>(e0, pb,           lists,               c.x, t * 64, c0, out, smem); return; }
  t -= t0;
  if (t < t1) { gemm_heavy< 256,  4>(e1, pb + 1048576, lists + (size_t)n,   c.y, t * 64, c0, out, smem); return; }
  t -= t1;
  if (t < t2) { gemm_light<64>(e2, pb + 1310720, lists + (size_t)2 * n, c.z, t * 64, c0, out, smem); return; }
  t -= t2;
  if (t < t3) { gemm_light<16>(e3, pb + 1376256, lists + (size_t)3 * n, c.w, t * 64, c0, out, smem); return; }
}

// ---------------------------------------------------------------------------
// Input order (setup_inputs dict order, verified rounds 1-19):
// inp, emb0, proj0, emb1, proj1, emb2, proj2, emb3, proj3.
// ws bytes: [0,16) counts | [16,1040) blkcnt | [1040,263184) lists |
// [524288, 3309568) pb bf16.
// ---------------------------------------------------------------------------
extern "C" void kernel_launch(void* const* d_in, const int* in_sizes, int n_in,
                              void* d_out, int out_size, void* d_ws, size_t ws_size,
                              hipStream_t stream) {
  const int*   inp   = (const int*)d_in[0];
  const float* emb0  = (const float*)d_in[1];
  const float* proj0 = (const float*)d_in[2];
  const float* emb1  = (const float*)d_in[3];
  const float* proj1 = (const float*)d_in[4];
  const float* emb2  = (const float*)d_in[5];
  const float* proj2 = (const float*)d_in[6];
  const float* emb3  = (const float*)d_in[7];
  const float* proj3 = (const float*)d_in[8];
  float* out = (float*)d_out;
  const int n = in_sizes[0];  // 16384 tokens

  int*            counts = (int*)d_ws;
  int*            blkcnt = (int*)d_ws + 4;
  unsigned*       lists  = (unsigned*)d_ws + 260;
  unsigned short* pb     = (unsigned short*)((char*)d_ws + 524288);

  const int nb = (n + 255) / 256;           // 64 (scan supports <= 64)
  convert_count<<<dim3(680), dim3(256), 0, stream>>>(proj0, proj1, proj2, proj3,
                                                     pb, inp, n, nb, blkcnt);
  scatter_kernel<<<dim3(nb), dim3(256), 0, stream>>>(inp, n, blkcnt, nb, lists, counts);

  // tiles: sum_i ceil(cnt_i/64) <= n/64 + 3 = 259; pad to 264 (multiple of 8).
  dim3 grid(264 * 8, 1, 1);
  size_t smem_bytes = 24576 + 64 * sizeof(unsigned);  // 24832 B -> 6 blocks/CU
  gemm_all<<<grid, dim3(256), smem_bytes, stream>>>(emb0, emb1, emb2, emb3, pb,
                                                    counts, lists, out, n);
}